// Round 9
// baseline (563.271 us; speedup 1.0000x reference)
//
#include <hip/hip_runtime.h>
#include <hip/hip_bf16.h>

// B=2, H=8, S=2048, D=64, fp32 in/out.
// out = concat(attention [B,H,S,S], sum_value [B,H,S,D]) fp32.
#define SS 2048
#define DD 64
#define HH 8
#define NB 2
#define NTT 8           // 64-key tiles per k-group (512 keys / group)
#define SCL 0.18033688011112042f   // (1/8) * log2(e)

typedef __bf16 bf16x8 __attribute__((ext_vector_type(8)));
typedef float f32x4 __attribute__((ext_vector_type(4)));

__device__ __forceinline__ unsigned short f2bf(float f) {
  unsigned int u = __float_as_uint(f);
  u += 0x7fff + ((u >> 16) & 1);   // RNE
  return (unsigned short)(u >> 16);
}
union U8 { ushort4 u[2]; bf16x8 v; };
__device__ __forceinline__ bf16x8 ld8(const ushort* p) {
  U8 t;
  t.u[0] = *(const ushort4*)p;
  t.u[1] = *(const ushort4*)(p + 4);
  return t.v;
}
// 8 consecutive fp32 from global -> bf16x8 fragment (f2bf scalar path, verified R0-R2)
__device__ __forceinline__ bf16x8 kfrag(const float* p) {
  float4 f0 = *(const float4*)p;
  float4 f1 = *(const float4*)(p + 4);
  U8 t;
  t.u[0] = make_ushort4(f2bf(f0.x), f2bf(f0.y), f2bf(f0.z), f2bf(f0.w));
  t.u[1] = make_ushort4(f2bf(f1.x), f2bf(f1.y), f2bf(f1.z), f2bf(f1.w));
  return t.v;
}
// XCD swizzle: 512 blocks -> 8 XCDs; each XCD gets 2 consecutive bh values.
__device__ __forceinline__ void decode(int& qt, int& bh) {
  int lin = blockIdx.x + 32 * blockIdx.y;        // 0..511
  int wid = (lin & 7) * 64 + (lin >> 3);         // bijective
  qt = wid & 31; bh = wid >> 5;
}

// One fused kernel. Block = 1024 threads = 16 waves = 4 q-slabs x 4 k-groups.
// Each block: one (bh), 64 queries, all 2048 keys (512/group).
// Pass A: per-group partial row sums (swapped QK^T, K-frags from global, no LDS,
//         no barriers) -> combine via Lred LDS.
// Pass B: recompute scores, direct coalesced attention stores from regs,
//         PV per group -> combine via LDS overlay, coalesced sv store.
__global__ __launch_bounds__(1024, 4) void attn_kernel(
    const float* __restrict__ Q, const float* __restrict__ K,
    const float* __restrict__ V, const int* __restrict__ maskp,
    float* __restrict__ attn, float* __restrict__ sv) {
  __shared__ ushort Vt[4][64][76];   // per-group V^T: Vt[grp][d][key]
  __shared__ ushort Pb[16][16][76];  // per-wave normalized P (bf16) [q][key]
  __shared__ float Lred[16][16];     // per-wave partial row sums

  int qt, bh; decode(qt, bh);
  const int tid = threadIdx.x, lane = tid & 63, w = tid >> 6;
  const int grp = w >> 2;        // k-group 0..3 (keys [grp*512, grp*512+512))
  const int wl = w & 3;          // q-slab within group
  const int t2 = tid & 255;      // thread within group
  const int col = lane & 15, g = lane >> 4;
  const int q0 = qt * 64, kb0 = grp * 512, b = bh >> 3;
  const size_t bhSD = (size_t)bh * SS * DD;

  // Q fragment (B-operand): col n = q = q0 + wl*16 + col
  bf16x8 aq[2];
  {
    const float* qrow = Q + bhSD + (size_t)(q0 + wl * 16 + col) * DD;
    #pragma unroll
    for (int s = 0; s < 2; ++s)
      aq[s] = kfrag(qrow + s * 32 + g * 8);
  }
  const int qg = q0 + wl * 16 + col;
  const float* Kbase = K + bhSD + (size_t)kb0 * DD;
  const int* mbase = maskp + b * SS + kb0;

  // =============== Pass A: partial row sums (no LDS, no barriers) ========
  float lacc = 0.f;
  for (int kt = 0; kt < NTT; ++kt) {
    const float* kb = Kbase + kt * 64 * DD;
    f32x4 acc[4] = {};
    #pragma unroll
    for (int s = 0; s < 2; ++s) {
      #pragma unroll
      for (int c = 0; c < 4; ++c) {
        bf16x8 ak = kfrag(kb + (c * 16 + col) * DD + s * 32 + g * 8);
        acc[c] = __builtin_amdgcn_mfma_f32_16x16x32_bf16(ak, aq[s], acc[c], 0, 0, 0);
      }
    }
    #pragma unroll
    for (int c = 0; c < 4; ++c) {
      int4 m4 = *(const int4*)&mbase[kt * 64 + c * 16 + g * 4];
      int mv[4] = {m4.x, m4.y, m4.z, m4.w};
      #pragma unroll
      for (int r = 0; r < 4; ++r) {
        int keyg = kb0 + kt * 64 + c * 16 + g * 4 + r;
        float p = (mv[r] != 0 || keyg == qg) ? 0.f : exp2f(acc[c][r] * SCL);
        lacc += p;
      }
    }
  }
  // butterfly over the 4 g-groups: every lane gets its q's group-partial
  lacc += __shfl_xor(lacc, 16);
  lacc += __shfl_xor(lacc, 32);
  if (g == 0) Lred[w][col] = lacc;
  __syncthreads();
  float ssum = Lred[wl][col] + Lred[4 + wl][col] + Lred[8 + wl][col] +
               Lred[12 + wl][col];
  const float inv_l = 1.0f / fmaxf(ssum, 1e-30f);   // NaN-proof

  // =============== Pass B: emit attention + PV ===========================
  float* arow = attn + ((size_t)bh * SS + qg) * SS + kb0;  // this lane's q row
  float4 vreg[4];
  {
    const float4* vs = (const float4*)(V + bhSD + (size_t)kb0 * DD);
    #pragma unroll
    for (int i = 0; i < 4; ++i) vreg[i] = vs[t2 + 256 * i];
  }

  f32x4 oacc[4] = {};
  for (int kt = 0; kt < NTT; ++kt) {
    __syncthreads();
    #pragma unroll
    for (int i = 0; i < 4; ++i) {
      int f = t2 + 256 * i, row = f >> 4, c4 = f & 15;
      float4 vv = vreg[i];
      int d0 = c4 * 4;
      Vt[grp][d0 + 0][row] = f2bf(vv.x);
      Vt[grp][d0 + 1][row] = f2bf(vv.y);
      Vt[grp][d0 + 2][row] = f2bf(vv.z);
      Vt[grp][d0 + 3][row] = f2bf(vv.w);
    }
    __syncthreads();
    if (kt + 1 < NTT) {   // prefetch next V tile during compute
      const float4* vs = (const float4*)(V + bhSD + (size_t)(kb0 + (kt + 1) * 64) * DD);
      #pragma unroll
      for (int i = 0; i < 4; ++i) vreg[i] = vs[t2 + 256 * i];
    }

    const float* kb = Kbase + kt * 64 * DD;
    f32x4 acc[4] = {};
    #pragma unroll
    for (int s = 0; s < 2; ++s) {
      #pragma unroll
      for (int c = 0; c < 4; ++c) {
        bf16x8 ak = kfrag(kb + (c * 16 + col) * DD + s * 32 + g * 8);
        acc[c] = __builtin_amdgcn_mfma_f32_16x16x32_bf16(ak, aq[s], acc[c], 0, 0, 0);
      }
    }

    // epilogue: exp -> normalized float4 attn store + Pb bf16 write
    #pragma unroll
    for (int c = 0; c < 4; ++c) {
      int4 m4 = *(const int4*)&mbase[kt * 64 + c * 16 + g * 4];
      int mv[4] = {m4.x, m4.y, m4.z, m4.w};
      f32x4 pn;
      #pragma unroll
      for (int r = 0; r < 4; ++r) {
        int keyg = kb0 + kt * 64 + c * 16 + g * 4 + r;
        float p = (mv[r] != 0 || keyg == qg) ? 0.f : exp2f(acc[c][r] * SCL);
        pn[r] = p * inv_l;
      }
      __builtin_nontemporal_store(pn, (f32x4*)&arow[kt * 64 + c * 16 + g * 4]);
      *(ushort4*)&Pb[w][col][c * 16 + g * 4] =
          make_ushort4(f2bf(pn[0]), f2bf(pn[1]), f2bf(pn[2]), f2bf(pn[3]));
    }

    // PV: A = P rows (Pb, wave-private), B = V^T (Vt[grp])
    #pragma unroll
    for (int s2 = 0; s2 < 2; ++s2) {
      bf16x8 pa = ld8(&Pb[w][col][s2 * 32 + g * 8]);
      #pragma unroll
      for (int c2 = 0; c2 < 4; ++c2) {
        bf16x8 bv = ld8(&Vt[grp][c2 * 16 + col][s2 * 32 + g * 8]);
        oacc[c2] = __builtin_amdgcn_mfma_f32_16x16x32_bf16(pa, bv, oacc[c2], 0, 0, 0);
      }
    }
  }

  // ---- combine PV partials across the 4 k-groups (LDS overlay on Pb) ----
  __syncthreads();                       // all Pb/Vt reads done
  float* comb = (float*)&Pb[0][0][0];    // [64][68] fp32 = 17.4 KB <= 38.9 KB
  #pragma unroll
  for (int gg = 0; gg < 4; ++gg) {
    if (grp == gg) {
      #pragma unroll
      for (int c2 = 0; c2 < 4; ++c2) {
        #pragma unroll
        for (int r = 0; r < 4; ++r) {
          int row = wl * 16 + g * 4 + r, d = c2 * 16 + col;
          if (gg == 0) comb[row * 68 + d] = oacc[c2][r];
          else         comb[row * 68 + d] += oacc[c2][r];
        }
      }
    }
    __syncthreads();
  }
  // cooperative coalesced sv store: 64 rows x 64 d fp32
  {
    int row = tid >> 4, c4 = (tid & 15) * 4;
    float4 val = make_float4(comb[row * 68 + c4], comb[row * 68 + c4 + 1],
                             comb[row * 68 + c4 + 2], comb[row * 68 + c4 + 3]);
    *(float4*)&sv[((size_t)bh * SS + q0 + row) * DD + c4] = val;
  }
}

extern "C" void kernel_launch(void* const* d_in, const int* in_sizes, int n_in,
                              void* d_out, int out_size, void* d_ws, size_t ws_size,
                              hipStream_t stream) {
  const float* Q = (const float*)d_in[0];
  const float* K = (const float*)d_in[1];
  const float* V = (const float*)d_in[2];
  const int* mask = (const int*)d_in[3];
  float* out = (float*)d_out;
  float* attn = out;                                   // B*H*S*S
  float* sv = out + (size_t)NB * HH * SS * SS;         // B*H*S*D
  dim3 grid(SS / 64, NB * HH);
  attn_kernel<<<grid, 1024, 0, stream>>>(Q, K, V, mask, attn, sv);
}

// Round 10
// 427.832 us; speedup vs baseline: 1.3166x; 1.3166x over previous
//
#include <hip/hip_runtime.h>
#include <hip/hip_bf16.h>

// B=2, H=8, S=2048, D=64, fp32 in/out.
// out = concat(attention [B,H,S,S], sum_value [B,H,S,D]) fp32.
#define SS 2048
#define DD 64
#define HH 8
#define NB 2
#define NKT 16          // 32-key tiles per k-group (512 keys/group)
#define SCL 0.18033688011112042f   // (1/8) * log2(e)

typedef __bf16 bf16x8 __attribute__((ext_vector_type(8)));
typedef float f32x4 __attribute__((ext_vector_type(4)));

__device__ __forceinline__ unsigned short f2bf(float f) {
  unsigned int u = __float_as_uint(f);
  u += 0x7fff + ((u >> 16) & 1);   // RNE
  return (unsigned short)(u >> 16);
}
union U8 { ushort4 u[2]; bf16x8 v; };
__device__ __forceinline__ bf16x8 ld8(const ushort* p) {
  U8 t;
  t.u[0] = *(const ushort4*)p;
  t.u[1] = *(const ushort4*)(p + 4);
  return t.v;
}
// 8 consecutive fp32 from global -> bf16x8 (used once, for Q)
__device__ __forceinline__ bf16x8 qfrag(const float* p) {
  float4 f0 = *(const float4*)p;
  float4 f1 = *(const float4*)(p + 4);
  U8 t;
  t.u[0] = make_ushort4(f2bf(f0.x), f2bf(f0.y), f2bf(f0.z), f2bf(f0.w));
  t.u[1] = make_ushort4(f2bf(f1.x), f2bf(f1.y), f2bf(f1.z), f2bf(f1.w));
  return t.v;
}
// XCD swizzle: 1024 blocks -> 8 XCDs; each XCD serves 2 bh (K/V L2-resident).
__device__ __forceinline__ void decode(int& qt, int& bh) {
  int lin = blockIdx.x + 64 * blockIdx.y;        // 0..1023
  int wid = (lin & 7) * 128 + (lin >> 3);        // bijective
  qt = wid & 63; bh = wid >> 6;
}

// Block = 512 thr = 8 waves = 2 q-slabs(16q) x 4 k-groups(512 keys).
// Each block: one bh, 32 queries, all 2048 keys.
// Pass A: LDS-staged K (32-key tiles), swapped QK^T, partial sums -> Lred.
// Pass B: restage K+V, recompute, reg-direct coalesced attn stores,
//         PV with A-frag staged into the wave's own Kb slice (overlay).
__global__ __launch_bounds__(512, 8) void attn_kernel(
    const float* __restrict__ Q, const float* __restrict__ K,
    const float* __restrict__ V, const int* __restrict__ maskp,
    float* __restrict__ attn, float* __restrict__ sv) {
  __shared__ ushort Kb[4][32][76];   // per-group K tile [key][d], stride 76
  __shared__ ushort Vt[4][64][44];   // per-group V^T [d][key], stride 44
  __shared__ float Lred[8][16];      // per-wave partial row sums

  int qt, bh; decode(qt, bh);
  const int tid = threadIdx.x, lane = tid & 63, w = tid >> 6;
  const int grp = w >> 1;        // k-group 0..3
  const int wl = w & 1;          // q-slab 0/1
  const int t128 = tid & 127;    // thread within k-group
  const int col = lane & 15, g = lane >> 4;
  const int q0 = qt * 32, kb0 = grp * 512, b = bh >> 3;
  const size_t bhSD = (size_t)bh * SS * DD;

  // Q fragment (B-operand): col j = q = q0 + wl*16 + col
  bf16x8 aq[2];
  {
    const float* qrow = Q + bhSD + (size_t)(q0 + wl * 16 + col) * DD;
    #pragma unroll
    for (int s = 0; s < 2; ++s) aq[s] = qfrag(qrow + s * 32 + g * 8);
  }
  const int qg = q0 + wl * 16 + col;
  const float* Kg = K + bhSD + (size_t)kb0 * DD;
  const float* Vg = V + bhSD + (size_t)kb0 * DD;
  const int* mbase = maskp + b * SS + kb0;

  // =============== Pass A: partial row sums ==============================
  float lacc = 0.f;
  for (int kt = 0; kt < NKT; ++kt) {
    __syncthreads();
    #pragma unroll
    for (int i = 0; i < 4; ++i) {   // stage K: 32x64 by 128 threads
      int f = t128 + 128 * i, key = f >> 4, c4 = f & 15;
      float4 kv = *(const float4*)(Kg + (size_t)(kt * 32 + key) * DD + c4 * 4);
      *(ushort4*)&Kb[grp][key][c4 * 4] =
          make_ushort4(f2bf(kv.x), f2bf(kv.y), f2bf(kv.z), f2bf(kv.w));
    }
    __syncthreads();
    f32x4 acc[2] = {};
    #pragma unroll
    for (int s = 0; s < 2; ++s) {
      #pragma unroll
      for (int c = 0; c < 2; ++c) {
        bf16x8 ak = ld8(&Kb[grp][c * 16 + col][s * 32 + g * 8]);
        acc[c] = __builtin_amdgcn_mfma_f32_16x16x32_bf16(ak, aq[s], acc[c], 0, 0, 0);
      }
    }
    #pragma unroll
    for (int c = 0; c < 2; ++c) {
      int4 m4 = *(const int4*)&mbase[kt * 32 + c * 16 + g * 4];
      int mv[4] = {m4.x, m4.y, m4.z, m4.w};
      #pragma unroll
      for (int r = 0; r < 4; ++r) {
        int keyg = kb0 + kt * 32 + c * 16 + g * 4 + r;
        float p = (mv[r] != 0 || keyg == qg) ? 0.f : exp2f(acc[c][r] * SCL);
        lacc += p;
      }
    }
  }
  lacc += __shfl_xor(lacc, 16);
  lacc += __shfl_xor(lacc, 32);
  if (g == 0) Lred[w][col] = lacc;
  __syncthreads();
  float ssum = Lred[wl][col] + Lred[2 + wl][col] + Lred[4 + wl][col] +
               Lred[6 + wl][col];
  const float inv_l = 1.0f / fmaxf(ssum, 1e-30f);   // NaN-proof

  // =============== Pass B: emit attention + PV ===========================
  float* arow = attn + ((size_t)bh * SS + qg) * SS + kb0;
  f32x4 oacc[4] = {};
  for (int kt = 0; kt < NKT; ++kt) {
    __syncthreads();
    #pragma unroll
    for (int i = 0; i < 4; ++i) {   // restage K
      int f = t128 + 128 * i, key = f >> 4, c4 = f & 15;
      float4 kv = *(const float4*)(Kg + (size_t)(kt * 32 + key) * DD + c4 * 4);
      *(ushort4*)&Kb[grp][key][c4 * 4] =
          make_ushort4(f2bf(kv.x), f2bf(kv.y), f2bf(kv.z), f2bf(kv.w));
    }
    #pragma unroll
    for (int i = 0; i < 4; ++i) {   // stage V transposed
      int f = t128 + 128 * i, key = f >> 4, c4 = f & 15;
      float4 vv = *(const float4*)(Vg + (size_t)(kt * 32 + key) * DD + c4 * 4);
      int d0 = c4 * 4;
      Vt[grp][d0 + 0][key] = f2bf(vv.x);
      Vt[grp][d0 + 1][key] = f2bf(vv.y);
      Vt[grp][d0 + 2][key] = f2bf(vv.z);
      Vt[grp][d0 + 3][key] = f2bf(vv.w);
    }
    __syncthreads();

    f32x4 acc[2] = {};
    #pragma unroll
    for (int s = 0; s < 2; ++s) {
      #pragma unroll
      for (int c = 0; c < 2; ++c) {
        bf16x8 ak = ld8(&Kb[grp][c * 16 + col][s * 32 + g * 8]);
        acc[c] = __builtin_amdgcn_mfma_f32_16x16x32_bf16(ak, aq[s], acc[c], 0, 0, 0);
      }
    }

    // epilogue: exp -> normalized float4 attn store (coalesced)
    ushort4 pw[2];
    #pragma unroll
    for (int c = 0; c < 2; ++c) {
      int4 m4 = *(const int4*)&mbase[kt * 32 + c * 16 + g * 4];
      int mv[4] = {m4.x, m4.y, m4.z, m4.w};
      f32x4 pn;
      #pragma unroll
      for (int r = 0; r < 4; ++r) {
        int keyg = kb0 + kt * 32 + c * 16 + g * 4 + r;
        float p = (mv[r] != 0 || keyg == qg) ? 0.f : exp2f(acc[c][r] * SCL);
        pn[r] = p * inv_l;
      }
      __builtin_nontemporal_store(pn, (f32x4*)&arow[kt * 32 + c * 16 + g * 4]);
      pw[c] = make_ushort4(f2bf(pn[0]), f2bf(pn[1]), f2bf(pn[2]), f2bf(pn[3]));
    }

    // P overlay into this wave's own Kb rows (K reads done by all kg waves)
    __syncthreads();
    #pragma unroll
    for (int c = 0; c < 2; ++c)
      *(ushort4*)&Kb[grp][wl * 16 + col][c * 16 + g * 4] = pw[c];

    // PV: A = P rows (own slice, wave-private), B = V^T; K-dim = 32 keys
    bf16x8 pa = ld8(&Kb[grp][wl * 16 + col][g * 8]);
    #pragma unroll
    for (int c2 = 0; c2 < 4; ++c2) {
      bf16x8 bv = ld8(&Vt[grp][c2 * 16 + col][g * 8]);
      oacc[c2] = __builtin_amdgcn_mfma_f32_16x16x32_bf16(pa, bv, oacc[c2], 0, 0, 0);
    }
  }

  // ---- combine PV partials across the 4 k-groups (LDS overlay on Kb) ----
  __syncthreads();
  float* comb = (float*)&Kb[0][0][0];    // [32][68] fp32 = 8.7 KB
  #pragma unroll
  for (int gg = 0; gg < 4; ++gg) {
    if (grp == gg) {
      #pragma unroll
      for (int c2 = 0; c2 < 4; ++c2) {
        #pragma unroll
        for (int r = 0; r < 4; ++r) {
          int row = wl * 16 + g * 4 + r, d = c2 * 16 + col;
          if (gg == 0) comb[row * 68 + d] = oacc[c2][r];
          else         comb[row * 68 + d] += oacc[c2][r];
        }
      }
    }
    __syncthreads();
  }
  // cooperative coalesced sv store: 32 rows x 64 d fp32 by 512 threads
  {
    int row = tid >> 4, c4 = (tid & 15) * 4;
    float4 val = make_float4(comb[row * 68 + c4], comb[row * 68 + c4 + 1],
                             comb[row * 68 + c4 + 2], comb[row * 68 + c4 + 3]);
    *(float4*)&sv[((size_t)bh * SS + q0 + row) * DD + c4] = val;
  }
}

extern "C" void kernel_launch(void* const* d_in, const int* in_sizes, int n_in,
                              void* d_out, int out_size, void* d_ws, size_t ws_size,
                              hipStream_t stream) {
  const float* Q = (const float*)d_in[0];
  const float* K = (const float*)d_in[1];
  const float* V = (const float*)d_in[2];
  const int* mask = (const int*)d_in[3];
  float* out = (float*)d_out;
  float* attn = out;                                   // B*H*S*S
  float* sv = out + (size_t)NB * HH * SS * SS;         // B*H*S*D
  dim3 grid(SS / 32, NB * HH);
  attn_kernel<<<grid, 512, 0, stream>>>(Q, K, V, mask, attn, sv);
}